// Round 1
// baseline (1445.885 us; speedup 1.0000x reference)
//
#include <hip/hip_runtime.h>
#include <math.h>

#define C_DIM 64
#define N_DIM 4096
#define B_DIM 8

// ---------------------------------------------------------------------------
// Kernel A: raw attention scores S[b] = X[b]^T X[b], X = [C=64, N=4096] fp32.
// One 64x64 output tile per block; K = C = 64 (single pass, both tiles in LDS).
// Writes raw scores into the attn region of d_out.
// ---------------------------------------------------------------------------
__global__ __launch_bounds__(256) void scores_kernel(const float* __restrict__ x,
                                                     float* __restrict__ attn) {
    __shared__ float As[64][64];   // As[k][i] = X[k, n0+i]  (rows of S)
    __shared__ float Bs[64][64];   // Bs[k][j] = X[k, m0+j]  (cols of S)

    const int b  = blockIdx.z;
    const int n0 = blockIdx.x * 64;
    const int m0 = blockIdx.y * 64;
    const float* xb = x + (size_t)b * C_DIM * N_DIM;
    const int t = threadIdx.x;

    // Load both 64x64 tiles: 4096 floats each, 4 float4 per thread, coalesced.
    for (int r = 0; r < 4; ++r) {
        int idx = (t + r * 256) * 4;   // 0..16380, step 4
        int k = idx >> 6;
        int i = idx & 63;
        *(float4*)&As[k][i] = *(const float4*)&xb[k * N_DIM + n0 + i];
        *(float4*)&Bs[k][i] = *(const float4*)&xb[k * N_DIM + m0 + i];
    }
    __syncthreads();

    const int ti = t & 15;   // row group (4 rows)
    const int tj = t >> 4;   // col group (4 cols)
    float acc[4][4] = {};
    for (int k = 0; k < 64; ++k) {
        float4 a4 = *(float4*)&As[k][ti * 4];
        float4 b4 = *(float4*)&Bs[k][tj * 4];
        float av[4] = {a4.x, a4.y, a4.z, a4.w};
        float bv[4] = {b4.x, b4.y, b4.z, b4.w};
        for (int ii = 0; ii < 4; ++ii)
            for (int jj = 0; jj < 4; ++jj)
                acc[ii][jj] = fmaf(av[ii], bv[jj], acc[ii][jj]);
    }

    const size_t base = (size_t)b * N_DIM * N_DIM;
    for (int ii = 0; ii < 4; ++ii) {
        int n = n0 + ti * 4 + ii;
        float4 v = make_float4(acc[ii][0], acc[ii][1], acc[ii][2], acc[ii][3]);
        *(float4*)&attn[base + (size_t)n * N_DIM + m0 + tj * 4] = v;
    }
}

// ---------------------------------------------------------------------------
// Kernel B: per-row max and 1/sum(exp(s-max)). One block per row (B*N rows).
// Row (4096 floats) lives in registers: 16 per thread. Wave shuffle + LDS reduce.
// ---------------------------------------------------------------------------
__global__ __launch_bounds__(256) void rowstat_kernel(const float* __restrict__ attn,
                                                      float2* __restrict__ stats) {
    const int row = blockIdx.x;                       // 0..B*N-1
    const float* s = attn + (size_t)row * N_DIM;
    const int t = threadIdx.x;

    float v[16];
    for (int r = 0; r < 4; ++r) {
        float4 f = *(const float4*)&s[r * 1024 + t * 4];
        v[r * 4 + 0] = f.x; v[r * 4 + 1] = f.y;
        v[r * 4 + 2] = f.z; v[r * 4 + 3] = f.w;
    }

    float m = -INFINITY;
    for (int i = 0; i < 16; ++i) m = fmaxf(m, v[i]);
    for (int off = 32; off; off >>= 1) m = fmaxf(m, __shfl_xor(m, off));

    __shared__ float redm[4];
    const int wave = t >> 6, lane = t & 63;
    if (lane == 0) redm[wave] = m;
    __syncthreads();
    m = fmaxf(fmaxf(redm[0], redm[1]), fmaxf(redm[2], redm[3]));

    float sum = 0.f;
    for (int i = 0; i < 16; ++i) sum += __expf(v[i] - m);
    for (int off = 32; off; off >>= 1) sum += __shfl_xor(sum, off);

    __shared__ float reds[4];
    if (lane == 0) reds[wave] = sum;
    __syncthreads();
    if (t == 0) {
        sum = reds[0] + reds[1] + reds[2] + reds[3];
        stats[row] = make_float2(m, 1.0f / sum);
    }
}

// ---------------------------------------------------------------------------
// Kernel C: normalize attn in place AND accumulate y = P * X^T.
// Block = 16 rows of one batch; loop over m in 64-wide chunks:
//   read S chunk -> p = exp(s-max)*inv -> write p -> stage p + X chunk in LDS
//   -> FMA into y[16][64] accumulators (4 c's per thread).
// ---------------------------------------------------------------------------
__global__ __launch_bounds__(256) void norm_y_kernel(const float* __restrict__ x,
                                                     const float2* __restrict__ stats,
                                                     float* __restrict__ attn,
                                                     float* __restrict__ y) {
    __shared__ float Ps[16][65];   // +1 pad: conflict-free row-major reads
    __shared__ float Xs[64][68];   // +4 pad: float4-aligned rows, 2-way max conflict
    __shared__ float smax[16], sinv[16];

    const int b  = blockIdx.y;
    const int n0 = blockIdx.x * 16;
    const int t  = threadIdx.x;

    if (t < 16) {
        float2 st = stats[b * N_DIM + n0 + t];
        smax[t] = st.x;
        sinv[t] = st.y;
    }
    __syncthreads();

    const int row = t & 15;          // compute: my output row
    const int c0  = (t >> 4) * 4;    // compute: my 4 channels
    const int lm  = t & 63;          // load: my m within chunk
    const int lr  = t >> 6;          // load: row group (rows lr, lr+4, lr+8, lr+12)
    const float* xb = x + (size_t)b * C_DIM * N_DIM;
    const size_t attn_row0 = ((size_t)b * N_DIM + n0) * N_DIM;

    float acc[4] = {0.f, 0.f, 0.f, 0.f};

    for (int mc = 0; mc < N_DIM; mc += 64) {
        // normalize 16x64 score chunk, write back, stage in LDS
        for (int rr = 0; rr < 4; ++rr) {
            int r = rr * 4 + lr;
            size_t idx = attn_row0 + (size_t)r * N_DIM + mc + lm;
            float sv = attn[idx];
            float p = __expf(sv - smax[r]) * sinv[r];
            attn[idx] = p;
            Ps[r][lm] = p;
        }
        // stage X chunk: Xs[c][m] = x[b, c, mc+m]
        for (int rr = 0; rr < 4; ++rr) {
            int idx = (t + rr * 256) * 4;   // 0..16380
            int c = idx >> 6;
            int m = idx & 63;
            float4 f = *(const float4*)&xb[c * N_DIM + mc + m];
            Xs[c][m + 0] = f.x; Xs[c][m + 1] = f.y;
            Xs[c][m + 2] = f.z; Xs[c][m + 3] = f.w;
        }
        __syncthreads();

        for (int m = 0; m < 64; ++m) {
            float p = Ps[row][m];
            for (int j = 0; j < 4; ++j)
                acc[j] = fmaf(p, Xs[c0 + j][m], acc[j]);
        }
        __syncthreads();
    }

    // y layout: [B, C, N] (== [B,C,H,W] flattened)
    for (int j = 0; j < 4; ++j)
        y[((size_t)b * C_DIM + c0 + j) * N_DIM + n0 + row] = acc[j];
}

extern "C" void kernel_launch(void* const* d_in, const int* in_sizes, int n_in,
                              void* d_out, int out_size, void* d_ws, size_t ws_size,
                              hipStream_t stream) {
    const float* x = (const float*)d_in[0];
    float* y    = (float*)d_out;                              // [8,64,64,64] = 2097152
    float* attn = (float*)d_out + (size_t)B_DIM * C_DIM * N_DIM; // [8,4096,4096]
    float2* stats = (float2*)d_ws;                            // 32768 rows

    dim3 gA(N_DIM / 64, N_DIM / 64, B_DIM);
    scores_kernel<<<gA, 256, 0, stream>>>(x, attn);

    rowstat_kernel<<<B_DIM * N_DIM, 256, 0, stream>>>(attn, stats);

    dim3 gC(N_DIM / 16, B_DIM);
    norm_y_kernel<<<gC, 256, 0, stream>>>(x, stats, attn, y);
}

// Round 2
// 714.566 us; speedup vs baseline: 2.0234x; 2.0234x over previous
//
#include <hip/hip_runtime.h>
#include <math.h>

#define BATCH 8
#define CD 64      // channels (K of the score GEMM)
#define ND 4096    // spatial positions
#define MR 128     // rows of attn per block

typedef short bf16x8 __attribute__((ext_vector_type(8)));
typedef float f32x4 __attribute__((ext_vector_type(4)));

static __device__ __forceinline__ unsigned short f2bf(float f) {
    unsigned int u = __float_as_uint(f);
    u += 0x7fff + ((u >> 16) & 1);   // RNE
    return (unsigned short)(u >> 16);
}
static __device__ __forceinline__ float bf2f(unsigned short h) {
    return __uint_as_float(((unsigned int)h) << 16);
}

// ---------------------------------------------------------------------------
// convert_kernel: x[b][c][n] fp32 ->
//   xt_hi/xt_lo [b][n][c] bf16 (split pair, for QK^T A/B fragments)
//   xcm_hi      [b][c][n] bf16 (for PV B fragments)
// ---------------------------------------------------------------------------
__global__ __launch_bounds__(256) void convert_kernel(const float* __restrict__ x,
        unsigned short* __restrict__ xt_hi, unsigned short* __restrict__ xt_lo,
        unsigned short* __restrict__ xcm_hi) {
    __shared__ unsigned short Thi[64][68];
    __shared__ unsigned short Tlo[64][68];
    const int b = blockIdx.y, n0 = blockIdx.x * 64, t = threadIdx.x;
    const float* xb = x + (size_t)b * CD * ND;

    for (int r = 0; r < 4; ++r) {
        int f4 = t + r * 256;            // 0..1023 float4 index in 64x64 tile
        int c  = f4 >> 4;
        int nc = (f4 & 15) * 4;
        float4 v = *(const float4*)&xb[(size_t)c * ND + n0 + nc];
        float vv[4] = {v.x, v.y, v.z, v.w};
        unsigned short h[4];
        unsigned long long packed = 0;
        for (int j = 0; j < 4; ++j) {
            h[j] = f2bf(vv[j]);
            unsigned short lo = f2bf(vv[j] - bf2f(h[j]));
            Thi[c][nc + j] = h[j];
            Tlo[c][nc + j] = lo;
            packed |= ((unsigned long long)h[j]) << (16 * j);
        }
        *(unsigned long long*)&xcm_hi[((size_t)b * CD + c) * ND + n0 + nc] = packed;
    }
    __syncthreads();

    // transposed write: thread t handles n = t>>2, c0 = (t&3)*16
    const int n = t >> 2, c0 = (t & 3) * 16;
    unsigned short hb[16], lb[16];
    for (int j = 0; j < 16; ++j) { hb[j] = Thi[c0 + j][n]; lb[j] = Tlo[c0 + j][n]; }
    size_t base = ((size_t)b * ND + n0 + n) * CD + c0;
    *(uint4*)&xt_hi[base]     = *(uint4*)&hb[0];
    *(uint4*)&xt_hi[base + 8] = *(uint4*)&hb[8];
    *(uint4*)&xt_lo[base]     = *(uint4*)&lb[0];
    *(uint4*)&xt_lo[base + 8] = *(uint4*)&lb[8];
}

// ---------------------------------------------------------------------------
// Fused attention: block = 256 threads (4 waves), owns 128 attn rows.
// Pass 1: S = X^T X via split-bf16 MFMA, online per-row max/sum (lane-local,
//         one 16-lane butterfly merge at the end).
// Pass 2: recompute S, p = exp(s-M)*inv -> attn (nontemporal), P through LDS
//         into A-fragment layout, y += P·X^T via bf16 MFMA.
// MFMA layouts (m89/m101/m120-verified):
//   A-frag: A[row = lane&15][k = (lane>>4)*8 + j]
//   B-frag: B[k = (lane>>4)*8 + j][col = lane&15]
//   C/D   : D[row = (lane>>4)*4 + reg][col = lane&15]
// ---------------------------------------------------------------------------
__global__ __launch_bounds__(256, 1) void attn_kernel(
        const unsigned short* __restrict__ xt_hi,
        const unsigned short* __restrict__ xt_lo,
        const unsigned short* __restrict__ xcm_hi,
        float* __restrict__ y, float* __restrict__ attn) {
    extern __shared__ char smem[];
    unsigned short (*Ahi)[72] = (unsigned short(*)[72])(smem);          // [128][72]
    unsigned short (*Alo)[72] = (unsigned short(*)[72])(smem + 18432);  // [128][72]
    unsigned short (*Bhi)[72] = (unsigned short(*)[72])(smem + 36864);  // [64][72]
    unsigned short (*Blo)[72] = (unsigned short(*)[72])(smem + 46080);  // [64][72]
    unsigned short (*Xpv)[72] = (unsigned short(*)[72])(smem + 55296);  // [64][72]
    unsigned short (*Ppv)[72] = (unsigned short(*)[72])(smem + 64512);  // [128][72]
    // total 82944 B -> 1 block/CU

    const int t  = threadIdx.x;
    const int w  = t >> 6;      // wave 0..3, owns rows w*32..w*32+31
    const int l  = t & 63;
    const int q  = l >> 4;      // quad
    const int lc = l & 15;
    const int b  = blockIdx.y;
    const int n0 = blockIdx.x * MR;

    const unsigned short* xthi_b = xt_hi + (size_t)b * ND * CD;
    const unsigned short* xtlo_b = xt_lo + (size_t)b * ND * CD;
    const unsigned short* xcm_b  = xcm_hi + (size_t)b * CD * ND;
    float* attn_b = attn + (size_t)b * ND * ND;

    // stage A tiles (this block's 128 rows), hi+lo
    for (int r = 0; r < 4; ++r) {
        int u = t + r * 256;           // 0..1023 (uint4 units)
        int row = u >> 3;
        int k8  = (u & 7) * 8;
        *(uint4*)&Ahi[row][k8] = *(const uint4*)&xthi_b[(size_t)(n0 + row) * CD + k8];
        *(uint4*)&Alo[row][k8] = *(const uint4*)&xtlo_b[(size_t)(n0 + row) * CD + k8];
    }

    float runmax[2][4], runsum[2][4];
    #pragma unroll
    for (int rt = 0; rt < 2; ++rt)
        #pragma unroll
        for (int i = 0; i < 4; ++i) { runmax[rt][i] = -INFINITY; runsum[rt][i] = 0.f; }

    // ------------------------- pass 1: stats -------------------------
    for (int m0 = 0; m0 < ND; m0 += 64) {
        __syncthreads();
        for (int r = 0; r < 2; ++r) {
            int u = t * 2 + r;         // 0..511
            int row = u >> 3;
            int k8  = (u & 7) * 8;
            *(uint4*)&Bhi[row][k8] = *(const uint4*)&xthi_b[(size_t)(m0 + row) * CD + k8];
            *(uint4*)&Blo[row][k8] = *(const uint4*)&xtlo_b[(size_t)(m0 + row) * CD + k8];
        }
        __syncthreads();

        bf16x8 ah[2][2], al[2][2];
        #pragma unroll
        for (int rt = 0; rt < 2; ++rt)
            #pragma unroll
            for (int ks = 0; ks < 2; ++ks) {
                int row = w * 32 + rt * 16 + lc;
                ah[rt][ks] = *(const bf16x8*)(const void*)&Ahi[row][ks * 32 + q * 8];
                al[rt][ks] = *(const bf16x8*)(const void*)&Alo[row][ks * 32 + q * 8];
            }
        f32x4 accs[2][4];
        #pragma unroll
        for (int ct = 0; ct < 4; ++ct) {
            bf16x8 bh[2], bl[2];
            #pragma unroll
            for (int ks = 0; ks < 2; ++ks) {
                bh[ks] = *(const bf16x8*)(const void*)&Bhi[ct * 16 + lc][ks * 32 + q * 8];
                bl[ks] = *(const bf16x8*)(const void*)&Blo[ct * 16 + lc][ks * 32 + q * 8];
            }
            #pragma unroll
            for (int rt = 0; rt < 2; ++rt) {
                f32x4 acc = {0.f, 0.f, 0.f, 0.f};
                #pragma unroll
                for (int ks = 0; ks < 2; ++ks) {
                    acc = __builtin_amdgcn_mfma_f32_16x16x32_bf16(ah[rt][ks], bh[ks], acc, 0, 0, 0);
                    acc = __builtin_amdgcn_mfma_f32_16x16x32_bf16(ah[rt][ks], bl[ks], acc, 0, 0, 0);
                    acc = __builtin_amdgcn_mfma_f32_16x16x32_bf16(al[rt][ks], bh[ks], acc, 0, 0, 0);
                }
                accs[rt][ct] = acc;
            }
        }
        #pragma unroll
        for (int rt = 0; rt < 2; ++rt)
            #pragma unroll
            for (int i = 0; i < 4; ++i) {
                float v0 = accs[rt][0][i], v1 = accs[rt][1][i];
                float v2 = accs[rt][2][i], v3 = accs[rt][3][i];
                float lm = fmaxf(fmaxf(v0, v1), fmaxf(v2, v3));
                float M  = fmaxf(runmax[rt][i], lm);
                float s  = __expf(v0 - M) + __expf(v1 - M) + __expf(v2 - M) + __expf(v3 - M);
                runsum[rt][i] = runsum[rt][i] * __expf(runmax[rt][i] - M) + s;
                runmax[rt][i] = M;
            }
    }

    // merge (max,sum) across the 16 lanes (same quad) holding each row
    #pragma unroll
    for (int rt = 0; rt < 2; ++rt)
        #pragma unroll
        for (int i = 0; i < 4; ++i) {
            float M = runmax[rt][i], S = runsum[rt][i];
            #pragma unroll
            for (int off = 1; off < 16; off <<= 1) {
                float M2 = __shfl_xor(M, off);
                float S2 = __shfl_xor(S, off);
                float Mn = fmaxf(M, M2);
                S = S * __expf(M - Mn) + S2 * __expf(M2 - Mn);
                M = Mn;
            }
            runmax[rt][i] = M;
            runsum[rt][i] = 1.0f / S;   // now holds inv
        }

    // ------------------- pass 2: write p, accumulate y -------------------
    f32x4 pvacc[2][4];
    #pragma unroll
    for (int rt = 0; rt < 2; ++rt)
        #pragma unroll
        for (int ct = 0; ct < 4; ++ct) { f32x4 z = {0.f,0.f,0.f,0.f}; pvacc[rt][ct] = z; }

    for (int m0 = 0; m0 < ND; m0 += 64) {
        __syncthreads();
        for (int r = 0; r < 2; ++r) {
            int u = t * 2 + r;
            int row = u >> 3;
            int k8  = (u & 7) * 8;
            *(uint4*)&Bhi[row][k8] = *(const uint4*)&xthi_b[(size_t)(m0 + row) * CD + k8];
            *(uint4*)&Blo[row][k8] = *(const uint4*)&xtlo_b[(size_t)(m0 + row) * CD + k8];
            *(uint4*)&Xpv[row][k8] = *(const uint4*)&xcm_b[(size_t)row * ND + m0 + k8];
        }
        __syncthreads();

        bf16x8 ah[2][2], al[2][2];
        #pragma unroll
        for (int rt = 0; rt < 2; ++rt)
            #pragma unroll
            for (int ks = 0; ks < 2; ++ks) {
                int row = w * 32 + rt * 16 + lc;
                ah[rt][ks] = *(const bf16x8*)(const void*)&Ahi[row][ks * 32 + q * 8];
                al[rt][ks] = *(const bf16x8*)(const void*)&Alo[row][ks * 32 + q * 8];
            }
        f32x4 accs[2][4];
        #pragma unroll
        for (int ct = 0; ct < 4; ++ct) {
            bf16x8 bh[2], bl[2];
            #pragma unroll
            for (int ks = 0; ks < 2; ++ks) {
                bh[ks] = *(const bf16x8*)(const void*)&Bhi[ct * 16 + lc][ks * 32 + q * 8];
                bl[ks] = *(const bf16x8*)(const void*)&Blo[ct * 16 + lc][ks * 32 + q * 8];
            }
            #pragma unroll
            for (int rt = 0; rt < 2; ++rt) {
                f32x4 acc = {0.f, 0.f, 0.f, 0.f};
                #pragma unroll
                for (int ks = 0; ks < 2; ++ks) {
                    acc = __builtin_amdgcn_mfma_f32_16x16x32_bf16(ah[rt][ks], bh[ks], acc, 0, 0, 0);
                    acc = __builtin_amdgcn_mfma_f32_16x16x32_bf16(ah[rt][ks], bl[ks], acc, 0, 0, 0);
                    acc = __builtin_amdgcn_mfma_f32_16x16x32_bf16(al[rt][ks], bh[ks], acc, 0, 0, 0);
                }
                accs[rt][ct] = acc;
            }
        }

        // softmax -> attn (nontemporal) + Ppv (bf16, [n][m] layout)
        #pragma unroll
        for (int rt = 0; rt < 2; ++rt)
            #pragma unroll
            for (int ct = 0; ct < 4; ++ct)
                #pragma unroll
                for (int i = 0; i < 4; ++i) {
                    float p = __expf(accs[rt][ct][i] - runmax[rt][i]) * runsum[rt][i];
                    int rloc = w * 32 + rt * 16 + q * 4 + i;
                    __builtin_nontemporal_store(p,
                        &attn_b[(size_t)(n0 + rloc) * ND + m0 + ct * 16 + lc]);
                    Ppv[rloc][ct * 16 + lc] = f2bf(p);
                }
        __asm__ volatile("s_waitcnt lgkmcnt(0)" ::: "memory");  // wave-local P visibility

        // PV: y-tile += P (A-frag) * Xpv (B-frag)
        #pragma unroll
        for (int rt = 0; rt < 2; ++rt)
            #pragma unroll
            for (int ks = 0; ks < 2; ++ks) {
                bf16x8 pa = *(const bf16x8*)(const void*)&Ppv[w * 32 + rt * 16 + lc][ks * 32 + q * 8];
                #pragma unroll
                for (int ct = 0; ct < 4; ++ct) {
                    bf16x8 xv = *(const bf16x8*)(const void*)&Xpv[ct * 16 + lc][ks * 32 + q * 8];
                    pvacc[rt][ct] = __builtin_amdgcn_mfma_f32_16x16x32_bf16(pa, xv, pvacc[rt][ct], 0, 0, 0);
                }
            }
    }

    // y[b][c][n], 4 consecutive n per store
    #pragma unroll
    for (int rt = 0; rt < 2; ++rt)
        #pragma unroll
        for (int ct = 0; ct < 4; ++ct) {
            int c = ct * 16 + lc;
            int n = n0 + w * 32 + rt * 16 + q * 4;
            float4 v = make_float4(pvacc[rt][ct][0], pvacc[rt][ct][1],
                                   pvacc[rt][ct][2], pvacc[rt][ct][3]);
            *(float4*)&y[((size_t)b * CD + c) * ND + n] = v;
        }
}

extern "C" void kernel_launch(void* const* d_in, const int* in_sizes, int n_in,
                              void* d_out, int out_size, void* d_ws, size_t ws_size,
                              hipStream_t stream) {
    const float* x = (const float*)d_in[0];
    float* y    = (float*)d_out;
    float* attn = (float*)d_out + (size_t)BATCH * CD * ND;

    // ws: xt_hi | xt_lo | xcm_hi, each 8*4096*64 bf16 = 4 MB (12 MB total)
    unsigned short* xt_hi  = (unsigned short*)d_ws;
    unsigned short* xt_lo  = xt_hi + (size_t)BATCH * ND * CD;
    unsigned short* xcm_hi = xt_lo + (size_t)BATCH * ND * CD;

    hipFuncSetAttribute(reinterpret_cast<const void*>(attn_kernel),
                        hipFuncAttributeMaxDynamicSharedMemorySize, 82944);

    convert_kernel<<<dim3(ND / 64, BATCH), 256, 0, stream>>>(x, xt_hi, xt_lo, xcm_hi);
    attn_kernel<<<dim3(ND / MR, BATCH), 256, 82944, stream>>>(xt_hi, xt_lo, xcm_hi, y, attn);
}